// Round 9
// baseline (113.424 us; speedup 1.0000x reference)
//
#include <hip/hip_runtime.h>

// FirUpsample R8: two-stage form (R5 math) with A (= w bf16) fully LDS-resident.
//   Stage 1 (MFMA): h = dilated conv3x3(x,w) as 4 parity-plane GEMMs
//     (K-depth 4/2/2/1 x 256 ic = 10.3 G MAC).
//   Stage 2 (VALU): separable 4-tap FIR on h (bf16 in LDS), fp32 out.
// Key change vs R5-R7: NO per-chunk A-restage. Block owns 32 ocs; full
// As[9][32][256] bf16 (144 KB, XOR-swizzled) preloaded ONCE (coalesced float4),
// reused across 16 K-chunks x 4 btile-reps. x-stage double-buffered (issue
// loads -> MFMA -> write -> 1 barrier). Waves plane-grouped for A-frag reuse.
// LDS plan (160256 B static): As [0,147456) | xs dbuf 2x5760 at 147456
// | hl[4][8][10][20] (12800 B) aliases xs region during epilogue.

typedef short bf16x8 __attribute__((ext_vector_type(8)));
typedef short short4v __attribute__((ext_vector_type(4)));
typedef float f32x16 __attribute__((ext_vector_type(16)));
typedef float f32x4v __attribute__((ext_vector_type(4)));

static __device__ __forceinline__ short f2bf(float f) {
  union { float f; unsigned u; } v; v.f = f;
  unsigned r = (v.u + 0x7FFFu + ((v.u >> 16) & 1u)) >> 16;
  return (short)r;
}
static __device__ __forceinline__ float bf2f(short s) {
  union { unsigned u; float f; } v; v.u = ((unsigned)(unsigned short)s) << 16;
  return v.f;
}

#define XS_OFF 147456
#define XS_SZ  5760

__global__ __launch_bounds__(512, 1)
void fir_up_v8(const float* __restrict__ x, const float* __restrict__ w,
               float* __restrict__ out) {
  __shared__ __align__(16) char smem[160256];
  char* Ab = smem;

  const int bid = blockIdx.x;
  const int octile = bid & 7;          // XCD bid&7 owns one octile's w-slice (L2)
  const int atile = (bid >> 3) & 7;
  const int n = bid >> 6;              // 0..3
  const int A0 = atile * 8;

  const int tid = threadIdx.x;
  const int wid = tid >> 6;
  const int lane = tid & 63;
  const int l31 = lane & 31, q = lane >> 5;
  const int swzA = (l31 & 7) << 4;

  // ---- one-time preload: w slice (32 oc x 256 ic x 9) -> As, coalesced ----
  for (int r = 0; r < 36; ++r) {
    const int f = tid + r * 512;
    const int oc = f / 576;
    const int rem = f - oc * 576;
    const f32x4v v = *(const f32x4v*)(w + (size_t)(octile * 32 + oc) * 2304 + rem * 4);
#pragma unroll
    for (int e = 0; e < 4; ++e) {
      const int flat = rem * 4 + e;
      const int ic = flat / 9;
      const int kq = flat - ic * 9;
      const int byte = (kq * 16384 + oc * 512 + ic * 2) ^ ((oc & 7) << 4);
      *(short*)(Ab + byte) = f2bf(v[e]);
    }
  }

  // ---- plane geometry & per-wave partition ----
  // p = py*2+px; rows: even-y 9, odd-y 10; cols: even-x 17, odd-x 18
  const int COLSt[4]  = {17, 18, 17, 18};
  const int CELLSt[4] = {153, 162, 170, 180};
  const int NKt[4]    = {4, 2, 2, 1};
  const int KQt[4][4] = {{0,2,6,8},{1,7,7,7},{3,5,5,5},{4,4,4,4}};
  const int DYt[4][4] = {{0,0,1,1},{0,1,1,1},{0,0,0,0},{0,0,0,0}};
  const int DXt[4][4] = {{0,1,0,1},{0,0,0,0},{0,1,1,1},{0,0,0,0}};
  // waves: w0 p0{0,1} w1 p0{2,3} w2 p0{4}+p3{4,5} w3 p1{0,1,2} w4 p1{3,4,5}
  //        w5 p2{0,1,2} w6 p2{3,4,5} w7 p3{0,1,2,3}   (K-steps 8,8,6,6,6,6,6,4)
  const int SEG0P[8]   = {0,0,0,1,1,2,2,3};
  const int SEG0FGB[8] = {0,2,4,0,3,0,3,0};
  const int SEG0NFG[8] = {2,2,1,3,3,3,3,4};

  const int p0w = SEG0P[wid];
  const int nk0 = NKt[p0w];
  const int nfg0 = SEG0NFG[wid];
  int aoff0[4];
#pragma unroll
  for (int s = 0; s < 4; ++s) aoff0[s] = KQt[p0w][s] * 16384 + l31 * 512 + q * 16;
  int bcell0[4][4], valid0[4], hbase0[4];
#pragma unroll
  for (int fg = 0; fg < 4; ++fg) {
    const int cellraw = (SEG0FGB[wid] + fg) * 32 + l31;
    const int valid = cellraw < CELLSt[p0w];
    const int cell = valid ? cellraw : 0;
    const int cols = COLSt[p0w];
    const int r = cell / cols;
    const int c = cell - r * cols;
    valid0[fg] = valid;
    hbase0[fg] = p0w * 1600 + r * 20 + c;
#pragma unroll
    for (int s = 0; s < 4; ++s)
      bcell0[fg][s] = (r + DYt[p0w][s]) * 18 + (c + DXt[p0w][s]);
  }
  // w2's second segment: p3, fgs {4,5} -> acc[1],acc[2]
  const int aoff1 = 4 * 16384 + l31 * 512 + q * 16;
  int bcell1[2], valid1[2], hbase1[2];
#pragma unroll
  for (int j = 0; j < 2; ++j) {
    const int cellraw = (4 + j) * 32 + l31;
    const int valid = cellraw < 180;
    const int cell = valid ? cellraw : 0;
    const int r = cell / 18;
    const int c = cell - r * 18;
    valid1[j] = valid;
    hbase1[j] = 3 * 1600 + r * 20 + c;
    bcell1[j] = r * 18 + c;      // p3: dy=dx=0
  }

  __syncthreads();  // As ready

  const float kf4[4] = {0.25f, 0.75f, 0.75f, 0.25f};

  // ---- btile reps: 4 x (K-loop over 16 ic-chunks + FIR epilogue) ----
  for (int btile = 0; btile < 4; ++btile) {
    const int B0 = btile * 16;

    f32x16 acc[4];
#pragma unroll
    for (int fg = 0; fg < 4; ++fg)
#pragma unroll
      for (int e = 0; e < 16; ++e) acc[fg][e] = 0.f;

    // x-stage unit (per thread, tid<360): cell = tid>>1, half = tid&1
    const int ucell = tid >> 1, uhalf = tid & 1;
    const int uhh = ucell / 18, uww = ucell - uhh * 18;
    const int ugh = A0 - 1 + uhh, ugw = B0 - 1 + uww;
    const bool uok = (tid < 360) & (ugh >= 0) & (ugh < 64) & (ugw >= 0) & (ugw < 64);
    const float* uxp = x + (((size_t)(n * 256 + uhalf * 8)) * 64 + ugh) * 64 + ugw;
    const int uwb = ucell * 32 + uhalf * 16;  // xs byte offset

    // prologue: stage chunk 0 -> xs half 0
    if (tid < 360) {
      bf16x8 vv;
#pragma unroll
      for (int e = 0; e < 8; ++e) {
        const float f = uok ? uxp[(size_t)e * 4096] : 0.f;
        vv[e] = f2bf(f);
      }
      *(bf16x8*)(smem + XS_OFF + uwb) = vv;
    }
    __syncthreads();

    for (int cc = 0; cc < 16; ++cc) {
      char* xr = smem + XS_OFF + (cc & 1) * XS_SZ;
      char* xw = smem + XS_OFF + ((cc & 1) ^ 1) * XS_SZ;

      // issue next chunk's loads early (latency hides under MFMA)
      float ld[8];
      const bool have = (cc < 15) && (tid < 360);
      if (have) {
        const float* xp = uxp + (size_t)(cc + 1) * 16 * 4096;
#pragma unroll
        for (int e = 0; e < 8; ++e) ld[e] = uok ? xp[(size_t)e * 4096] : 0.f;
      }

      // MFMA on chunk cc
#pragma unroll
      for (int s = 0; s < 4; ++s) {
        if (s < nk0) {
          const bf16x8 A = *(const bf16x8*)(Ab + ((aoff0[s] + cc * 32) ^ swzA));
#pragma unroll
          for (int fg = 0; fg < 4; ++fg) {
            if (fg < nfg0) {
              const bf16x8 B = *(const bf16x8*)(xr + bcell0[fg][s] * 32 + q * 16);
              acc[fg] = __builtin_amdgcn_mfma_f32_32x32x16_bf16(A, B, acc[fg], 0, 0, 0);
            }
          }
        }
      }
      if (wid == 2) {
        const bf16x8 A = *(const bf16x8*)(Ab + ((aoff1 + cc * 32) ^ swzA));
#pragma unroll
        for (int j = 0; j < 2; ++j) {
          const bf16x8 B = *(const bf16x8*)(xr + bcell1[j] * 32 + q * 16);
          acc[1 + j] = __builtin_amdgcn_mfma_f32_32x32x16_bf16(A, B, acc[1 + j], 0, 0, 0);
        }
      }

      // write staged chunk
      if (have) {
        bf16x8 vv;
#pragma unroll
        for (int e = 0; e < 8; ++e) vv[e] = f2bf(ld[e]);
        *(bf16x8*)(xw + uwb) = vv;
      }
      __syncthreads();
    }

    // ---- epilogue: 4 sub-phases of 8 ocs; hl[4][8][10][20] aliases xs ----
    short* hl = (short*)(smem + XS_OFF);
#pragma unroll
    for (int g8 = 0; g8 < 4; ++g8) {
      // h-write: D-row = (e&3)+8*(e>>2)+4q; e = 4*g8+jj -> ocl8 = jj+4q
#pragma unroll
      for (int fg = 0; fg < 4; ++fg) {
        if (fg < nfg0 && valid0[fg]) {
#pragma unroll
          for (int jj = 0; jj < 4; ++jj)
            hl[hbase0[fg] + (jj + 4 * q) * 200] = f2bf(acc[fg][4 * g8 + jj]);
        }
      }
      if (wid == 2) {
#pragma unroll
        for (int j = 0; j < 2; ++j) {
          if (valid1[j]) {
#pragma unroll
            for (int jj = 0; jj < 4; ++jj)
              hl[hbase1[j] + (jj + 4 * q) * 200] = f2bf(acc[1 + j][4 * g8 + jj]);
          }
        }
      }
      __syncthreads();

      // FIR: one unit per thread (8 ocl x 16 Yl x 4 g = 512)
      const int g = tid & 3;
      const int Yl = (tid >> 2) & 15;
      const int o8 = tid >> 6;
      float o[8];
#pragma unroll
      for (int xx = 0; xx < 8; ++xx) o[xx] = 0.f;
#pragma unroll
      for (int du = 0; du < 4; ++du) {
        const int ttp = Yl - 1 + du;
        const int py = ttp & 1;
        const int r = py ? ((Yl + du) >> 1) : (ttp >> 1);
        const int baseE = (py * 2) * 1600 + o8 * 200 + r * 20 + 4 * g;
        const int baseO = baseE + 1600;
        const short4v e0 = *(const short4v*)(hl + baseE);
        const short4v e1 = *(const short4v*)(hl + baseE + 4);
        const short4v o0 = *(const short4v*)(hl + baseO);
        const short4v o1 = *(const short4v*)(hl + baseO + 4);
        float E[8], O[8];
#pragma unroll
        for (int i = 0; i < 4; ++i) {
          E[i] = bf2f(e0[i]); E[i + 4] = bf2f(e1[i]);
          O[i] = bf2f(o0[i]); O[i + 4] = bf2f(o1[i]);
        }
        float rx[8];
        rx[0] = 0.25f*O[0] + 0.75f*E[0] + 0.75f*O[1] + 0.25f*E[1];
        rx[1] = 0.25f*E[0] + 0.75f*O[1] + 0.75f*E[1] + 0.25f*O[2];
        rx[2] = 0.25f*O[1] + 0.75f*E[1] + 0.75f*O[2] + 0.25f*E[2];
        rx[3] = 0.25f*E[1] + 0.75f*O[2] + 0.75f*E[2] + 0.25f*O[3];
        rx[4] = 0.25f*O[2] + 0.75f*E[2] + 0.75f*O[3] + 0.25f*E[3];
        rx[5] = 0.25f*E[2] + 0.75f*O[3] + 0.75f*E[3] + 0.25f*O[4];
        rx[6] = 0.25f*O[3] + 0.75f*E[3] + 0.75f*O[4] + 0.25f*E[4];
        rx[7] = 0.25f*E[3] + 0.75f*O[4] + 0.75f*E[4] + 0.25f*O[5];
        const float ky = kf4[du];
#pragma unroll
        for (int xx = 0; xx < 8; ++xx) o[xx] += ky * rx[xx];
      }
      const int oc = octile * 32 + g8 * 8 + o8;
      const int Y = atile * 16 + Yl;
      const int X0 = btile * 32 + g * 8;
      float* op = out + (((size_t)(n * 256 + oc)) * 128 + Y) * 128 + X0;
      f32x4v v0, v1;
      v0[0] = o[0]; v0[1] = o[1]; v0[2] = o[2]; v0[3] = o[3];
      v1[0] = o[4]; v1[1] = o[5]; v1[2] = o[6]; v1[3] = o[7];
      *(f32x4v*)op = v0;
      *(f32x4v*)(op + 4) = v1;
      __syncthreads();  // hl free for next sub-phase / next rep's xs staging
    }
  }
}

extern "C" void kernel_launch(void* const* d_in, const int* in_sizes, int n_in,
                              void* d_out, int out_size, void* d_ws, size_t ws_size,
                              hipStream_t stream) {
  (void)in_sizes; (void)n_in; (void)out_size; (void)d_ws; (void)ws_size;
  const float* x = (const float*)d_in[0];
  const float* w = (const float*)d_in[1];
  float* out = (float*)d_out;
  // grid = 8 octiles x 4 n x 8 atiles = 256 blocks (1/CU), 512 threads
  hipLaunchKernelGGL(fir_up_v8, dim3(256), dim3(512), 0, stream, x, w, out);
}

// Round 10
// 106.996 us; speedup vs baseline: 1.0601x; 1.0601x over previous
//
#include <hip/hip_runtime.h>

// FirUpsample R9: same two-stage math as R5-R8 (h = dilated conv3x3 as 4
// parity-plane GEMMs, 10.3 G MAC; then separable 4-tap FIR in VALU), but
// restructured for OCCUPANCY: R5-R8 all ran ~105us with every pipe idle
// (Mfma 9%, VALU 26%, HBM <27%, occ 21%) -- 1 block/CU, 8 waves, barrier-
// serialized latency. R9: LDS 14.6 KB (per-chunk As restage + xs; hl aliases
// both in epilogue), __launch_bounds__(512,4) -> 2+ blocks/CU co-resident to
// hide latency; grid 1024 (one btile per block); spatial-grouped XCD swizzle
// (x slice 2.9 MB L2-resident per XCD); 4-way-max LDS bank swizzle.

typedef short bf16x4 __attribute__((ext_vector_type(4)));
typedef short bf16x8 __attribute__((ext_vector_type(8)));
typedef short short4v __attribute__((ext_vector_type(4)));
typedef float f32x16 __attribute__((ext_vector_type(16)));
typedef float f32x4v __attribute__((ext_vector_type(4)));

static __device__ __forceinline__ short f2bf(float f) {
  union { float f; unsigned u; } v; v.f = f;
  unsigned r = (v.u + 0x7FFFu + ((v.u >> 16) & 1u)) >> 16;
  return (short)r;
}
static __device__ __forceinline__ float bf2f(short s) {
  union { unsigned u; float f; } v; v.u = ((unsigned)(unsigned short)s) << 16;
  return v.f;
}

#define XS_OFF 9216   // As [0,9216) | xs [9216,14976) | hl aliases [0,12800)

__global__ __launch_bounds__(512, 4)
void fir_up_v9(const float* __restrict__ x, const float* __restrict__ w,
               float* __restrict__ out) {
  __shared__ __align__(16) char smem[14976];
  char* Ab = smem;
  char* xb = smem + XS_OFF;

  const int bid = blockIdx.x;
  // XCD swizzle: xcd = bid&7 owns 16 consecutive sp-tiles (x slice ~2.9MB L2)
  const int wg = (bid & 7) * 128 + (bid >> 3);
  const int octile = wg & 7;           // 0..7 (32 ocs)
  const int sp = wg >> 3;              // 0..127
  const int n = sp >> 5;
  const int atile = (sp >> 2) & 7;
  const int btile = sp & 3;
  const int A0 = atile * 8, B0 = btile * 16;

  const int tid = threadIdx.x;
  const int wid = tid >> 6;
  const int lane = tid & 63;
  const int l31 = lane & 31, q = lane >> 5;

  // ---- plane geometry (verbatim R8, verified) ----
  const int COLSt[4]  = {17, 18, 17, 18};
  const int CELLSt[4] = {153, 162, 170, 180};
  const int NKt[4]    = {4, 2, 2, 1};
  const int KQt[4][4] = {{0,2,6,8},{1,7,7,7},{3,5,5,5},{4,4,4,4}};
  const int DYt[4][4] = {{0,0,1,1},{0,1,1,1},{0,0,0,0},{0,0,0,0}};
  const int DXt[4][4] = {{0,1,0,1},{0,0,0,0},{0,1,1,1},{0,0,0,0}};
  // waves: w0 p0{0,1} w1 p0{2,3} w2 p0{4}+p3{4,5} w3 p1{0,1,2} w4 p1{3,4,5}
  //        w5 p2{0,1,2} w6 p2{3,4,5} w7 p3{0,1,2,3}
  const int SEG0P[8]   = {0,0,0,1,1,2,2,3};
  const int SEG0FGB[8] = {0,2,4,0,3,0,3,0};
  const int SEG0NFG[8] = {2,2,1,3,3,3,3,4};

  const int p0w = SEG0P[wid];
  const int nk0 = NKt[p0w];
  const int nfg0 = SEG0NFG[wid];
  // A-read byte offsets (constant per thread; As restaged to same spot each chunk)
  int aoff0[4];
#pragma unroll
  for (int s = 0; s < 4; ++s)
    aoff0[s] = KQt[p0w][s] * 1024 + l31 * 32 + ((q * 16) ^ ((l31 & 4) << 2));
  int boff0[4][4], valid0[4], hbase0[4];
#pragma unroll
  for (int fg = 0; fg < 4; ++fg) {
    const int cellraw = (SEG0FGB[wid] + fg) * 32 + l31;
    const int valid = cellraw < CELLSt[p0w];
    const int cell = valid ? cellraw : 0;
    const int cols = COLSt[p0w];
    const int r = cell / cols;
    const int c = cell - r * cols;
    valid0[fg] = valid;
    hbase0[fg] = p0w * 1600 + r * 20 + c;
#pragma unroll
    for (int s = 0; s < 4; ++s) {
      const int bc = (r + DYt[p0w][s]) * 18 + (c + DXt[p0w][s]);
      boff0[fg][s] = bc * 32 + ((q * 16) ^ ((bc & 4) << 2));
    }
  }
  // w2's second segment: p3, fgs {4,5} -> acc[1],acc[2]
  const int aoff1 = 4 * 1024 + l31 * 32 + ((q * 16) ^ ((l31 & 4) << 2));
  int boff1[2], valid1[2], hbase1[2];
#pragma unroll
  for (int j = 0; j < 2; ++j) {
    const int cellraw = (4 + j) * 32 + l31;
    const int valid = cellraw < 180;
    const int cell = valid ? cellraw : 0;
    const int r = cell / 18;
    const int c = cell - r * 18;
    valid1[j] = valid;
    hbase1[j] = 3 * 1600 + r * 20 + c;
    boff1[j] = cell * 32 + ((q * 16) ^ ((cell & 4) << 2));
  }

  f32x16 acc[4];
#pragma unroll
  for (int fg = 0; fg < 4; ++fg)
#pragma unroll
    for (int e = 0; e < 16; ++e) acc[fg][e] = 0.f;

  // staging constants
  // A-units: threads 0..127, unit = (ocA in 32, icgA in 4)
  const int ocA = tid >> 2, icgA = tid & 3;
  const float* wA = w + (size_t)(octile * 32 + ocA) * 2304 + icgA * 36;
  const int awb = ocA * 32 + (((icgA * 8) & 15) ^ ((ocA & 4) << 2)) + ((icgA & 2) << 3);
  // NOTE: icg*8 in [0,32): slot-XOR applies within 16-B slots ->
  // byte = oc*32 + ((icg*8) ^ 16*((oc&4)>>2)) computed below directly.
  // x-units: threads 128..487, unit u = tid-128 in [0,360)
  const int u = tid - 128;
  const int ucell = u >> 1, uhalf = u & 1;
  const int uhh = ucell / 18, uww = ucell - uhh * 18;
  const int ugh = A0 - 1 + uhh, ugw = B0 - 1 + uww;
  const bool uok = (ugh >= 0) & (ugh < 64) & (ugw >= 0) & (ugw < 64);
  const float* uxp = x + (((size_t)(n * 256 + uhalf * 8)) * 64 + ugh) * 64 + ugw;
  const int uwb = ucell * 32 + ((uhalf * 16) ^ ((ucell & 4) << 2));

  // ---------------- K-loop: 16 chunks of 16 ic ----------------
  for (int cc = 0; cc < 16; ++cc) {
    if (tid < 128) {
      // stage A: 36 contiguous floats, transpose in regs, 9 x b64 writes
      float f36[36];
      const float* wp = wA + cc * 144;
#pragma unroll
      for (int f4 = 0; f4 < 9; ++f4)
        *(f32x4v*)&f36[f4 * 4] = *(const f32x4v*)(wp + f4 * 4);
#pragma unroll
      for (int kq = 0; kq < 9; ++kq) {
        bf16x4 pk;
#pragma unroll
        for (int v = 0; v < 4; ++v) pk[v] = f2bf(f36[v * 9 + kq]);
        const int byte = kq * 1024 + ocA * 32 + ((icgA * 8) ^ ((ocA & 4) << 2));
        *(bf16x4*)(Ab + byte) = pk;
      }
    } else if (tid < 488) {
      // stage x: one (cell, 8-ic half) unit
      const float* xp = uxp + (size_t)cc * 16 * 4096;
      bf16x8 vv;
#pragma unroll
      for (int e = 0; e < 8; ++e) {
        const float f = uok ? xp[(size_t)e * 4096] : 0.f;
        vv[e] = f2bf(f);
      }
      *(bf16x8*)(xb + uwb) = vv;
    }
    __syncthreads();

    // MFMA (R8 partition; single A-frag, acc[4])
#pragma unroll
    for (int s = 0; s < 4; ++s) {
      if (s < nk0) {
        const bf16x8 A = *(const bf16x8*)(Ab + aoff0[s]);
#pragma unroll
        for (int fg = 0; fg < 4; ++fg) {
          if (fg < nfg0) {
            const bf16x8 B = *(const bf16x8*)(xb + boff0[fg][s]);
            acc[fg] = __builtin_amdgcn_mfma_f32_32x32x16_bf16(A, B, acc[fg], 0, 0, 0);
          }
        }
      }
    }
    if (wid == 2) {
      const bf16x8 A = *(const bf16x8*)(Ab + aoff1);
#pragma unroll
      for (int j = 0; j < 2; ++j) {
        const bf16x8 B = *(const bf16x8*)(xb + boff1[j]);
        acc[1 + j] = __builtin_amdgcn_mfma_f32_32x32x16_bf16(A, B, acc[1 + j], 0, 0, 0);
      }
    }
    __syncthreads();  // readers done before next restage
  }

  // ---------------- epilogue: 4 sub-phases of 8 ocs; hl aliases As/xs ----------------
  short* hl = (short*)smem;
  const float kf4[4] = {0.25f, 0.75f, 0.75f, 0.25f};
#pragma unroll
  for (int g8 = 0; g8 < 4; ++g8) {
    // h-write: acc elem e = 4*g8+jj -> ocl8 = jj + 4q
#pragma unroll
    for (int fg = 0; fg < 4; ++fg) {
      if (fg < nfg0 && valid0[fg]) {
#pragma unroll
        for (int jj = 0; jj < 4; ++jj)
          hl[hbase0[fg] + (jj + 4 * q) * 200] = f2bf(acc[fg][4 * g8 + jj]);
      }
    }
    if (wid == 2) {
#pragma unroll
      for (int j = 0; j < 2; ++j) {
        if (valid1[j]) {
#pragma unroll
          for (int jj = 0; jj < 4; ++jj)
            hl[hbase1[j] + (jj + 4 * q) * 200] = f2bf(acc[1 + j][4 * g8 + jj]);
        }
      }
    }
    __syncthreads();

    // FIR: one unit per thread (8 ocl x 16 Yl x 4 g = 512)
    const int g = tid & 3;
    const int Yl = (tid >> 2) & 15;
    const int o8 = tid >> 6;
    float o[8];
#pragma unroll
    for (int xx = 0; xx < 8; ++xx) o[xx] = 0.f;
#pragma unroll
    for (int du = 0; du < 4; ++du) {
      const int ttp = Yl - 1 + du;
      const int py = ttp & 1;
      const int r = py ? ((Yl + du) >> 1) : (ttp >> 1);
      const int baseE = (py * 2) * 1600 + o8 * 200 + r * 20 + 4 * g;
      const int baseO = baseE + 1600;
      const short4v e0 = *(const short4v*)(hl + baseE);
      const short4v e1 = *(const short4v*)(hl + baseE + 4);
      const short4v o0 = *(const short4v*)(hl + baseO);
      const short4v o1 = *(const short4v*)(hl + baseO + 4);
      float E[8], O[8];
#pragma unroll
      for (int i = 0; i < 4; ++i) {
        E[i] = bf2f(e0[i]); E[i + 4] = bf2f(e1[i]);
        O[i] = bf2f(o0[i]); O[i + 4] = bf2f(o1[i]);
      }
      float rx[8];
      rx[0] = 0.25f*O[0] + 0.75f*E[0] + 0.75f*O[1] + 0.25f*E[1];
      rx[1] = 0.25f*E[0] + 0.75f*O[1] + 0.75f*E[1] + 0.25f*O[2];
      rx[2] = 0.25f*O[1] + 0.75f*E[1] + 0.75f*O[2] + 0.25f*E[2];
      rx[3] = 0.25f*E[1] + 0.75f*O[2] + 0.75f*E[2] + 0.25f*O[3];
      rx[4] = 0.25f*O[2] + 0.75f*E[2] + 0.75f*O[3] + 0.25f*E[3];
      rx[5] = 0.25f*E[2] + 0.75f*O[3] + 0.75f*E[3] + 0.25f*O[4];
      rx[6] = 0.25f*O[3] + 0.75f*E[3] + 0.75f*O[4] + 0.25f*E[4];
      rx[7] = 0.25f*E[3] + 0.75f*O[4] + 0.75f*E[4] + 0.25f*O[5];
      const float ky = kf4[du];
#pragma unroll
      for (int xx = 0; xx < 8; ++xx) o[xx] += ky * rx[xx];
    }
    const int oc = octile * 32 + g8 * 8 + o8;
    const int Y = atile * 16 + Yl;
    const int X0 = btile * 32 + g * 8;
    float* op = out + (((size_t)(n * 256 + oc)) * 128 + Y) * 128 + X0;
    f32x4v v0, v1;
    v0[0] = o[0]; v0[1] = o[1]; v0[2] = o[2]; v0[3] = o[3];
    v1[0] = o[4]; v1[1] = o[5]; v1[2] = o[6]; v1[3] = o[7];
    *(f32x4v*)op = v0;
    *(f32x4v*)(op + 4) = v1;
    __syncthreads();  // hl free for next sub-phase
  }
}

extern "C" void kernel_launch(void* const* d_in, const int* in_sizes, int n_in,
                              void* d_out, int out_size, void* d_ws, size_t ws_size,
                              hipStream_t stream) {
  (void)in_sizes; (void)n_in; (void)out_size; (void)d_ws; (void)ws_size;
  const float* x = (const float*)d_in[0];
  const float* w = (const float*)d_in[1];
  float* out = (float*)d_out;
  // grid = 8 octiles x 4 n x 8 atiles x 4 btiles = 1024 blocks, 512 threads
  hipLaunchKernelGGL(fir_up_v9, dim3(1024), dim3(512), 0, stream, x, w, out);
}